// Round 2
// baseline (2047.329 us; speedup 1.0000x reference)
//
#include <hip/hip_runtime.h>
#include <math.h>

// LSTM: B=64, T=2048, I=200, H=100. Output h_T [64,100] fp32.
//   prep_kernel : transpose W_ih -> Wt[200][512], bias = b_ih+b_hh,
//                 Whh_pad[400][112] (k padded 100->112 with zeros)
//   xproj_kernel: xg[b,t,g] = x[b,t,:].Wt[:,g] + bias[g]  (fp32, pk_fma packed)
//   lstm_kernel : 64 WGs (one per batch), 512 thr (8 waves = 2/SIMD for latency
//                 overlap). Thread (q=tid>>2, s4=tid&3) owns ALL 4 gates of unit q
//                 over a QUARTER of h (28 elems): 7 ds_read_b128 + 56 pk_fma/step.
//                 Full quad sum via 2-stage DPP butterfly; xg folded into the
//                 butterfly (1 load/thread/step, prefetched 2 steps ahead).
//                 One barrier per step.

#define T_TOTAL 2048
#define B_SZ 64
#define IN_SZ 200
#define H_SZ 100
#define GP 512   // padded gate dim (4*H=400 -> 512)
#define KP 112   // padded hidden dim for Whh rows (100 -> 112, quarter = 28)

typedef float v2f __attribute__((ext_vector_type(2)));

__device__ __forceinline__ float sigf(float x) {
    return __builtin_amdgcn_rcpf(1.f + __expf(-x));
}

// quad_perm DPP move of x with given control (bound_ctrl=true)
#define QSWAP(x, ctrl) \
    __int_as_float(__builtin_amdgcn_mov_dpp(__float_as_int(x), ctrl, 0xF, 0xF, true))

// ---------------- prep ----------------
__global__ void prep_kernel(const float* __restrict__ W_ih,
                            const float* __restrict__ W_hh,
                            const float* __restrict__ b_ih,
                            const float* __restrict__ b_hh,
                            float* __restrict__ Wt,
                            float* __restrict__ bias,
                            float* __restrict__ Whp) {
    int idx = blockIdx.x * 256 + threadIdx.x;
    if (idx < IN_SZ * GP) {
        int k = idx >> 9;
        int g = idx & (GP - 1);
        Wt[idx] = (g < 400) ? W_ih[g * IN_SZ + k] : 0.f;
    }
    if (idx < GP) bias[idx] = (idx < 400) ? (b_ih[idx] + b_hh[idx]) : 0.f;
    if (idx < 400 * KP) {
        int g = idx / KP;
        int k = idx - g * KP;
        Whp[idx] = (k < H_SZ) ? W_hh[g * H_SZ + k] : 0.f;
    }
}

// ---------------- input projection GEMM (pk_fma packed) ----------------
__global__ __launch_bounds__(256, 4) void xproj_kernel(
    const float* __restrict__ x, const float* __restrict__ Wt,
    const float* __restrict__ bias, float* __restrict__ xg,
    int t0, int Tlen) {
    __shared__ __align__(16) float xTc[50][68];
    __shared__ __align__(16) float4 LW[50][32];

    const int tid = threadIdx.x;
    const int gblk = blockIdx.x;
    const int tbase = t0 + blockIdx.y * 64;
    const int b = blockIdx.z;
    const int gt = tid & 15;
    const int tt = tid >> 4;

    v2f acc[4][4];
#pragma unroll
    for (int r = 0; r < 4; ++r)
#pragma unroll
        for (int h = 0; h < 4; ++h) { acc[r][h].x = 0.f; acc[r][h].y = 0.f; }

    const float2* x2 = (const float2*)x;
    const float4* Wt4 = (const float4*)Wt;

    for (int kc = 0; kc < 4; ++kc) {
        for (int idx = tid; idx < 64 * 25; idx += 256) {
            int row = idx / 25, c2 = idx % 25;
            float2 v = x2[(size_t)(b * T_TOTAL + tbase + row) * (IN_SZ / 2) + kc * 25 + c2];
            xTc[c2 * 2][row] = v.x;
            xTc[c2 * 2 + 1][row] = v.y;
        }
        for (int idx = tid; idx < 50 * 32; idx += 256) {
            int k = idx >> 5, c = idx & 31;
            LW[k][c] = Wt4[(size_t)(kc * 50 + k) * (GP / 4) + gblk * 32 + c];
        }
        __syncthreads();

#pragma unroll 5
        for (int k = 0; k < 50; ++k) {
            float4 xv = *(const float4*)&xTc[k][tt * 4];
            float4 w0 = LW[k][gt];
            float4 w1 = LW[k][16 + gt];
            v2f wv[4];
            wv[0].x = w0.x; wv[0].y = w0.y; wv[1].x = w0.z; wv[1].y = w0.w;
            wv[2].x = w1.x; wv[2].y = w1.y; wv[3].x = w1.z; wv[3].y = w1.w;
            float xa[4] = {xv.x, xv.y, xv.z, xv.w};
#pragma unroll
            for (int tr = 0; tr < 4; ++tr) {
                v2f xs; xs.x = xa[tr]; xs.y = xa[tr];
#pragma unroll
                for (int h = 0; h < 4; ++h)
                    acc[tr][h] = __builtin_elementwise_fma(xs, wv[h], acc[tr][h]);
            }
        }
        __syncthreads();
    }

    const float4* bias4 = (const float4*)bias;
    float4 b0 = bias4[gblk * 32 + gt];
    float4 b1 = bias4[gblk * 32 + 16 + gt];
    float4* o4 = (float4*)xg;
#pragma unroll
    for (int tr = 0; tr < 4; ++tr) {
        int trow = (tbase - t0) + tt * 4 + tr;
        size_t o = (size_t)(b * Tlen + trow) * (GP / 4) + gblk * 32;
        float4 v0 = make_float4(acc[tr][0].x + b0.x, acc[tr][0].y + b0.y,
                                acc[tr][1].x + b0.z, acc[tr][1].y + b0.w);
        float4 v1 = make_float4(acc[tr][2].x + b1.x, acc[tr][2].y + b1.y,
                                acc[tr][3].x + b1.z, acc[tr][3].y + b1.w);
        o4[o + gt] = v0;
        o4[o + 16 + gt] = v1;
    }
}

// ---------------- recurrence: one WG (512 thr) per batch ----------------
// Thread (q = tid>>2 < 100, s4 = tid&3) owns gates {q, 100+q, 200+q, 300+q}
// over h-quarter s4 (k in [s4*28, s4*28+28), zero-padded). Per step:
//   7 x ds_read_b128 of h-quarter, 56 x v_pk_fma_f32 (4 gates x 14),
//   per-gate full-quad reduce via 2-stage DPP butterfly; lane s4 injects its
//   gate's xg value BEFORE the butterfly (so only 1 xg load/thread/step,
//   prefetched 2 steps ahead to cover HBM latency). All 4 lanes of a quad end
//   with d[0..3] complete and redundantly compute c,h; s4==0 writes h_q to the
//   other LDS buffer. ONE __syncthreads per step.
__global__ __attribute__((amdgpu_flat_work_group_size(512, 512), amdgpu_waves_per_eu(2, 2)))
void lstm_kernel(
    const float* __restrict__ xg, const float* __restrict__ Whp,
    float* __restrict__ hstate, float* __restrict__ cstate,
    float* __restrict__ out, int Tlen, int first, int last) {
    __shared__ __align__(16) float hlds[2][KP];  // double-buffered h[100] + pad

    const int b = blockIdx.x;
    const int tid = threadIdx.x;
    const int q = tid >> 2;
    const int s4 = tid & 3;
    const bool active = (q < H_SZ);

    // 4 gate quarter-rows: 4 x 14 v2f = 112 VGPRs.
    v2f w[4][14];
    if (active) {
        const v2f* W2 = (const v2f*)Whp;
#pragma unroll
        for (int g = 0; g < 4; ++g) {
            const v2f* row = W2 + (size_t)(g * H_SZ + q) * (KP / 2) + s4 * 14;
#pragma unroll
            for (int m = 0; m < 14; ++m) w[g][m] = row[m];
        }
    } else {
#pragma unroll
        for (int g = 0; g < 4; ++g)
#pragma unroll
            for (int m = 0; m < 14; ++m) { w[g][m].x = 0.f; w[g][m].y = 0.f; }
    }

    // xg injection selector: lane s4 contributes gate s4's x before the butterfly
    float sf[4];
#pragma unroll
    for (int g = 0; g < 4; ++g) sf[g] = (s4 == g) ? 1.f : 0.f;

    float c = 0.f;
    if (active) c = first ? 0.f : cstate[b * H_SZ + q];
    if (tid < KP) hlds[0][tid] = (tid < H_SZ) ? (first ? 0.f : hstate[b * H_SZ + tid]) : 0.f;
    if (tid < KP - H_SZ) hlds[1][H_SZ + tid] = 0.f;  // zero pad of buffer 1
    __syncthreads();

    // per-thread xg address: gate s4*100+q of batch b
    const size_t base = (size_t)b * Tlen * GP + (size_t)(s4 * H_SZ + q);
    float xv = active ? xg[base] : 0.f;
    float xn = (active && Tlen > 1) ? xg[base + GP] : 0.f;

    float hval = 0.f;
    for (int tl = 0; tl < Tlen; ++tl) {
        // prefetch 2 steps ahead (window ~2 iterations covers HBM latency)
        float xf = (active && (tl + 2) < Tlen) ? xg[base + (size_t)(tl + 2) * GP] : 0.f;

        const float4* hb4 = (const float4*)&hlds[tl & 1][s4 * 28];
        v2f a0[4], a1[4];
#pragma unroll
        for (int g = 0; g < 4; ++g) {
            a0[g].x = 0.f; a0[g].y = 0.f;
            a1[g].x = 0.f; a1[g].y = 0.f;
        }
#pragma unroll
        for (int m = 0; m < 7; ++m) {
            float4 h4 = hb4[m];
            v2f hlo; hlo.x = h4.x; hlo.y = h4.y;
            v2f hhi; hhi.x = h4.z; hhi.y = h4.w;
#pragma unroll
            for (int g = 0; g < 4; ++g) {
                a0[g] = __builtin_elementwise_fma(hlo, w[g][2 * m], a0[g]);
                a1[g] = __builtin_elementwise_fma(hhi, w[g][2 * m + 1], a1[g]);
            }
        }

        float d[4];
#pragma unroll
        for (int g = 0; g < 4; ++g) {
            v2f sv = a0[g] + a1[g];
            float p = sv.x + sv.y;
            p = __builtin_fmaf(sf[g], xv, p);     // inject x for gate g (lane s4==g)
            float p1 = p + QSWAP(p, 0xB1);        // [1,0,3,2]: pair sums
            d[g] = p1 + QSWAP(p1, 0x4E);          // [2,3,0,1]: full quad sum
        }

        float ai = sigf(d[0]);
        float af = sigf(d[1]);
        float ag = __builtin_fmaf(sigf(2.f * d[2]), 2.f, -1.f);  // tanh
        float ao = sigf(d[3]);
        c = __builtin_fmaf(af, c, ai * ag);
        float tc = __builtin_fmaf(sigf(2.f * c), 2.f, -1.f);     // tanh(c)
        hval = ao * tc;

        if (active && s4 == 0) hlds[(tl & 1) ^ 1][q] = hval;
        __syncthreads();
        xv = xn;
        xn = xf;
    }

    if (active && s4 == 0) {
        hstate[b * H_SZ + q] = hval;
        cstate[b * H_SZ + q] = c;
        if (last) out[b * H_SZ + q] = hval;
    }
}

// ---------------- host ----------------
extern "C" void kernel_launch(void* const* d_in, const int* in_sizes, int n_in,
                              void* d_out, int out_size, void* d_ws, size_t ws_size,
                              hipStream_t stream) {
    const float* x    = (const float*)d_in[0];
    const float* W_ih = (const float*)d_in[1];
    const float* W_hh = (const float*)d_in[2];
    const float* b_ih = (const float*)d_in[3];
    const float* b_hh = (const float*)d_in[4];
    float* out = (float*)d_out;

    char* ws = (char*)d_ws;
    float* Wt     = (float*)(ws);            // 200*512*4      = 409600
    float* bias   = (float*)(ws + 409600);   // 512*4          = 2048
    float* Whp    = (float*)(ws + 411648);   // 400*112*4      = 179200
    float* hstate = (float*)(ws + 590848);   // 64*100*4       = 25600
    float* cstate = (float*)(ws + 616448);   // 64*100*4       = 25600
    float* xgbuf  = (float*)(ws + 642048);

    size_t cap = (ws_size > 642048) ? (ws_size - 642048) : 0;
    long long tcmax = (long long)(cap / ((size_t)B_SZ * GP * 4));
    int Tc = (int)((tcmax / 64) * 64);
    if (Tc > T_TOTAL) Tc = T_TOTAL;
    if (Tc < 64) Tc = 64;

    prep_kernel<<<400, 256, 0, stream>>>(W_ih, W_hh, b_ih, b_hh, Wt, bias, Whp);

    for (int t0 = 0; t0 < T_TOTAL; t0 += Tc) {
        int Tlen = T_TOTAL - t0;
        if (Tlen > Tc) Tlen = Tc;
        xproj_kernel<<<dim3(4, Tlen / 64, B_SZ), 256, 0, stream>>>(x, Wt, bias, xgbuf, t0, Tlen);
        lstm_kernel<<<B_SZ, 512, 0, stream>>>(xgbuf, Whp, hstate, cstate, out,
                                              Tlen, t0 == 0 ? 1 : 0,
                                              (t0 + Tlen) == T_TOTAL ? 1 : 0);
    }
}

// Round 3
// 1710.726 us; speedup vs baseline: 1.1968x; 1.1968x over previous
//
#include <hip/hip_runtime.h>
#include <math.h>

// LSTM: B=64, T=2048, I=200, H=100. Output h_T [64,100] fp32.
//   prep_kernel : transpose W_ih -> Wt[200][512], bias = b_ih+b_hh,
//                 Whh_pad[400][112] (k padded 100->112 with zeros)
//   xproj_kernel: xg[b,t,g] = x[b,t,:].Wt[:,g] + bias[g]  (fp32, pk_fma packed)
//   lstm_kernel : 64 WGs (one per batch), 512 thr. Thread (q=tid>>2, s4=tid&3)
//                 owns all 4 gates of unit q over a QUARTER of h (28 elems).
//                 Time loop hand-unrolled x4: pipeline regs x0..x3, body b
//                 consumes x_b (loaded 4 steps earlier) and reloads it for t+4
//                 -> NO rotation movs, NO per-step vmcnt(0) stall (the bug that
//                 pinned rounds 0-2 at ~1500-1800 cyc/step). Static LDS
//                 double-buffer indices. One barrier per step.

#define T_TOTAL 2048
#define B_SZ 64
#define IN_SZ 200
#define H_SZ 100
#define GP 512   // padded gate dim (4*H=400 -> 512)
#define KP 112   // padded hidden dim for Whh rows (100 -> 112, quarter = 28)

typedef float v2f __attribute__((ext_vector_type(2)));

__device__ __forceinline__ float sigf(float x) {
    return __builtin_amdgcn_rcpf(1.f + __expf(-x));
}

// quad_perm DPP move of x with given control (bound_ctrl=true)
#define QSWAP(x, ctrl) \
    __int_as_float(__builtin_amdgcn_mov_dpp(__float_as_int(x), ctrl, 0xF, 0xF, true))

// ---------------- prep ----------------
__global__ void prep_kernel(const float* __restrict__ W_ih,
                            const float* __restrict__ W_hh,
                            const float* __restrict__ b_ih,
                            const float* __restrict__ b_hh,
                            float* __restrict__ Wt,
                            float* __restrict__ bias,
                            float* __restrict__ Whp) {
    int idx = blockIdx.x * 256 + threadIdx.x;
    if (idx < IN_SZ * GP) {
        int k = idx >> 9;
        int g = idx & (GP - 1);
        Wt[idx] = (g < 400) ? W_ih[g * IN_SZ + k] : 0.f;
    }
    if (idx < GP) bias[idx] = (idx < 400) ? (b_ih[idx] + b_hh[idx]) : 0.f;
    if (idx < 400 * KP) {
        int g = idx / KP;
        int k = idx - g * KP;
        Whp[idx] = (k < H_SZ) ? W_hh[g * H_SZ + k] : 0.f;
    }
}

// ---------------- input projection GEMM (pk_fma packed) ----------------
__global__ __launch_bounds__(256, 4) void xproj_kernel(
    const float* __restrict__ x, const float* __restrict__ Wt,
    const float* __restrict__ bias, float* __restrict__ xg,
    int t0, int Tlen) {
    __shared__ __align__(16) float xTc[50][68];
    __shared__ __align__(16) float4 LW[50][32];

    const int tid = threadIdx.x;
    const int gblk = blockIdx.x;
    const int tbase = t0 + blockIdx.y * 64;
    const int b = blockIdx.z;
    const int gt = tid & 15;
    const int tt = tid >> 4;

    v2f acc[4][4];
#pragma unroll
    for (int r = 0; r < 4; ++r)
#pragma unroll
        for (int h = 0; h < 4; ++h) { acc[r][h].x = 0.f; acc[r][h].y = 0.f; }

    const float2* x2 = (const float2*)x;
    const float4* Wt4 = (const float4*)Wt;

    for (int kc = 0; kc < 4; ++kc) {
        for (int idx = tid; idx < 64 * 25; idx += 256) {
            int row = idx / 25, c2 = idx % 25;
            float2 v = x2[(size_t)(b * T_TOTAL + tbase + row) * (IN_SZ / 2) + kc * 25 + c2];
            xTc[c2 * 2][row] = v.x;
            xTc[c2 * 2 + 1][row] = v.y;
        }
        for (int idx = tid; idx < 50 * 32; idx += 256) {
            int k = idx >> 5, c = idx & 31;
            LW[k][c] = Wt4[(size_t)(kc * 50 + k) * (GP / 4) + gblk * 32 + c];
        }
        __syncthreads();

#pragma unroll 5
        for (int k = 0; k < 50; ++k) {
            float4 xv = *(const float4*)&xTc[k][tt * 4];
            float4 w0 = LW[k][gt];
            float4 w1 = LW[k][16 + gt];
            v2f wv[4];
            wv[0].x = w0.x; wv[0].y = w0.y; wv[1].x = w0.z; wv[1].y = w0.w;
            wv[2].x = w1.x; wv[2].y = w1.y; wv[3].x = w1.z; wv[3].y = w1.w;
            float xa[4] = {xv.x, xv.y, xv.z, xv.w};
#pragma unroll
            for (int tr = 0; tr < 4; ++tr) {
                v2f xs; xs.x = xa[tr]; xs.y = xa[tr];
#pragma unroll
                for (int h = 0; h < 4; ++h)
                    acc[tr][h] = __builtin_elementwise_fma(xs, wv[h], acc[tr][h]);
            }
        }
        __syncthreads();
    }

    const float4* bias4 = (const float4*)bias;
    float4 b0 = bias4[gblk * 32 + gt];
    float4 b1 = bias4[gblk * 32 + 16 + gt];
    float4* o4 = (float4*)xg;
#pragma unroll
    for (int tr = 0; tr < 4; ++tr) {
        int trow = (tbase - t0) + tt * 4 + tr;
        size_t o = (size_t)(b * Tlen + trow) * (GP / 4) + gblk * 32;
        float4 v0 = make_float4(acc[tr][0].x + b0.x, acc[tr][0].y + b0.y,
                                acc[tr][1].x + b0.z, acc[tr][1].y + b0.w);
        float4 v1 = make_float4(acc[tr][2].x + b1.x, acc[tr][2].y + b1.y,
                                acc[tr][3].x + b1.z, acc[tr][3].y + b1.w);
        o4[o + gt] = v0;
        o4[o + 16 + gt] = v1;
    }
}

// ---------------- recurrence: one WG (512 thr) per batch ----------------
__global__ __attribute__((amdgpu_flat_work_group_size(512, 512), amdgpu_waves_per_eu(2, 2)))
void lstm_kernel(
    const float* __restrict__ xg, const float* __restrict__ Whp,
    float* __restrict__ hstate, float* __restrict__ cstate,
    float* __restrict__ out, int Tlen, int first, int last) {
    __shared__ __align__(16) float hlds[2][KP];  // double-buffered h[100] + pad

    const int b = blockIdx.x;
    const int tid = threadIdx.x;
    const int q = tid >> 2;
    const int s4 = tid & 3;
    const bool active = (q < H_SZ);

    // 4 gate quarter-rows: 4 x 14 v2f = 112 regs, resident.
    v2f w[4][14];
    if (active) {
        const v2f* W2 = (const v2f*)Whp;
#pragma unroll
        for (int g = 0; g < 4; ++g) {
            const v2f* row = W2 + (size_t)(g * H_SZ + q) * (KP / 2) + s4 * 14;
#pragma unroll
            for (int m = 0; m < 14; ++m) w[g][m] = row[m];
        }
    } else {
#pragma unroll
        for (int g = 0; g < 4; ++g)
#pragma unroll
            for (int m = 0; m < 14; ++m) { w[g][m].x = 0.f; w[g][m].y = 0.f; }
    }

    // xg injection selector: lane s4 contributes gate s4's x before the butterfly
    float sf[4];
#pragma unroll
    for (int g = 0; g < 4; ++g) sf[g] = (s4 == g) ? 1.f : 0.f;

    float c = 0.f;
    if (active) c = first ? 0.f : cstate[b * H_SZ + q];
    if (tid < KP) hlds[0][tid] = (tid < H_SZ) ? (first ? 0.f : hstate[b * H_SZ + tid]) : 0.f;
    if (tid < KP - H_SZ) hlds[1][H_SZ + tid] = 0.f;  // zero pad of buffer 1
    __syncthreads();

    // per-thread xg pointer: gate s4*100+q of batch b, stride GP floats per step
    const float* xp = xg + (size_t)b * Tlen * GP + (size_t)(s4 * H_SZ + q);

    // depth-4 register pipeline (Tlen >= 64 always, so steps 0..3 exist)
    float x0 = active ? xp[0 * GP] : 0.f;
    float x1 = active ? xp[1 * GP] : 0.f;
    float x2 = active ? xp[2 * GP] : 0.f;
    float x3 = active ? xp[3 * GP] : 0.f;

    float hval = 0.f;

    // One LSTM step: consume pipeline reg XB (step tcur), read hlds[RB],
    // write hlds[WB], reload XB for step tcur+4 (counted-vmcnt pipeline).
#define LSTM_STEP(XB, RB, WB, tcur)                                            \
    {                                                                          \
        const float4* hb4 = (const float4*)&hlds[RB][s4 * 28];                 \
        v2f a0[4], a1[4];                                                      \
        _Pragma("unroll") for (int g = 0; g < 4; ++g) {                        \
            a0[g].x = 0.f; a0[g].y = 0.f;                                      \
            a1[g].x = 0.f; a1[g].y = 0.f;                                      \
        }                                                                      \
        _Pragma("unroll") for (int m = 0; m < 7; ++m) {                        \
            float4 h4 = hb4[m];                                                \
            v2f hlo; hlo.x = h4.x; hlo.y = h4.y;                               \
            v2f hhi; hhi.x = h4.z; hhi.y = h4.w;                               \
            _Pragma("unroll") for (int g = 0; g < 4; ++g) {                    \
                a0[g] = __builtin_elementwise_fma(hlo, w[g][2 * m], a0[g]);    \
                a1[g] = __builtin_elementwise_fma(hhi, w[g][2 * m + 1], a1[g]);\
            }                                                                  \
        }                                                                      \
        float d[4];                                                            \
        _Pragma("unroll") for (int g = 0; g < 4; ++g) {                        \
            v2f sv = a0[g] + a1[g];                                            \
            float p = sv.x + sv.y;                                             \
            p = __builtin_fmaf(sf[g], XB, p);                                  \
            float p1 = p + QSWAP(p, 0xB1);                                     \
            d[g] = p1 + QSWAP(p1, 0x4E);                                       \
        }                                                                      \
        XB = (active && ((tcur) + 4) < Tlen) ? xp[(size_t)((tcur) + 4) * GP]   \
                                             : 0.f;                            \
        float ai = sigf(d[0]);                                                 \
        float af = sigf(d[1]);                                                 \
        float ag = __builtin_fmaf(sigf(2.f * d[2]), 2.f, -1.f);                \
        float ao = sigf(d[3]);                                                 \
        c = __builtin_fmaf(af, c, ai * ag);                                    \
        float tc = __builtin_fmaf(sigf(2.f * c), 2.f, -1.f);                   \
        hval = ao * tc;                                                        \
        if (active && s4 == 0) hlds[WB][q] = hval;                             \
        __syncthreads();                                                       \
    }

    for (int tl = 0; tl < Tlen; tl += 4) {
        LSTM_STEP(x0, 0, 1, tl + 0);
        LSTM_STEP(x1, 1, 0, tl + 1);
        LSTM_STEP(x2, 0, 1, tl + 2);
        LSTM_STEP(x3, 1, 0, tl + 3);
    }
#undef LSTM_STEP

    if (active && s4 == 0) {
        hstate[b * H_SZ + q] = hval;
        cstate[b * H_SZ + q] = c;
        if (last) out[b * H_SZ + q] = hval;
    }
}

// ---------------- host ----------------
extern "C" void kernel_launch(void* const* d_in, const int* in_sizes, int n_in,
                              void* d_out, int out_size, void* d_ws, size_t ws_size,
                              hipStream_t stream) {
    const float* x    = (const float*)d_in[0];
    const float* W_ih = (const float*)d_in[1];
    const float* W_hh = (const float*)d_in[2];
    const float* b_ih = (const float*)d_in[3];
    const float* b_hh = (const float*)d_in[4];
    float* out = (float*)d_out;

    char* ws = (char*)d_ws;
    float* Wt     = (float*)(ws);            // 200*512*4      = 409600
    float* bias   = (float*)(ws + 409600);   // 512*4          = 2048
    float* Whp    = (float*)(ws + 411648);   // 400*112*4      = 179200
    float* hstate = (float*)(ws + 590848);   // 64*100*4       = 25600
    float* cstate = (float*)(ws + 616448);   // 64*100*4       = 25600
    float* xgbuf  = (float*)(ws + 642048);

    size_t cap = (ws_size > 642048) ? (ws_size - 642048) : 0;
    long long tcmax = (long long)(cap / ((size_t)B_SZ * GP * 4));
    int Tc = (int)((tcmax / 64) * 64);
    if (Tc > T_TOTAL) Tc = T_TOTAL;
    if (Tc < 64) Tc = 64;

    prep_kernel<<<400, 256, 0, stream>>>(W_ih, W_hh, b_ih, b_hh, Wt, bias, Whp);

    for (int t0 = 0; t0 < T_TOTAL; t0 += Tc) {
        int Tlen = T_TOTAL - t0;
        if (Tlen > Tc) Tlen = Tc;
        xproj_kernel<<<dim3(4, Tlen / 64, B_SZ), 256, 0, stream>>>(x, Wt, bias, xgbuf, t0, Tlen);
        lstm_kernel<<<B_SZ, 512, 0, stream>>>(xgbuf, Whp, hstate, cstate, out,
                                              Tlen, t0 == 0 ? 1 : 0,
                                              (t0 + Tlen) == T_TOTAL ? 1 : 0);
    }
}

// Round 5
// 1565.239 us; speedup vs baseline: 1.3080x; 1.0929x over previous
//
#include <hip/hip_runtime.h>
#include <math.h>

// LSTM: B=64, T=2048, I=200, H=100. Output h_T [64,100] fp32.
//   prep_kernel : transpose W_ih -> Wt[200][512], bias = b_ih+b_hh,
//                 Whh_pad[400][112] (k padded 100->112 with zeros)
//   xproj_kernel: xg[b,t,g] = x[b,t,:].Wt[:,g] + bias[g]  (fp32, pk_fma packed)
//   lstm_kernel : 64 WGs (one per batch), 512 thr. Thread (q=tid>>2, s4=tid&3)
//                 owns all 4 gates of unit q over a QUARTER of h (28 elems).
//                 Time loop hand-unrolled x4 with pipeline regs x0..x3.
//                 KEY FIX vs rounds 0-3: the xg reload is UNCONDITIONAL
//                 (clamped pointer for inactive lanes, 4-step slack after the
//                 buffer instead of a bounds check). The old
//                 `cond ? load : 0` pattern forced a v_cndmask on the load
//                 result -> s_waitcnt vmcnt(0) EVERY STEP (~500 cyc exposed
//                 latency) -- the invariant ~1500 cyc/step floor of R0-R3.
//                 Now the load is consumed 4 steps after issue (counted wait).
// (Round 5 = identical resubmit of round 4: that bench died to a container
//  infra failure before running; the hypothesis is still untested.)

#define T_TOTAL 2048
#define B_SZ 64
#define IN_SZ 200
#define H_SZ 100
#define GP 512   // padded gate dim (4*H=400 -> 512)
#define KP 112   // padded hidden dim for Whh rows (100 -> 112, quarter = 28)

typedef float v2f __attribute__((ext_vector_type(2)));

__device__ __forceinline__ float sigf(float x) {
    return __builtin_amdgcn_rcpf(1.f + __expf(-x));
}

// quad_perm DPP move of x with given control (bound_ctrl=true)
#define QSWAP(x, ctrl) \
    __int_as_float(__builtin_amdgcn_mov_dpp(__float_as_int(x), ctrl, 0xF, 0xF, true))

// ---------------- prep ----------------
__global__ void prep_kernel(const float* __restrict__ W_ih,
                            const float* __restrict__ W_hh,
                            const float* __restrict__ b_ih,
                            const float* __restrict__ b_hh,
                            float* __restrict__ Wt,
                            float* __restrict__ bias,
                            float* __restrict__ Whp) {
    int idx = blockIdx.x * 256 + threadIdx.x;
    if (idx < IN_SZ * GP) {
        int k = idx >> 9;
        int g = idx & (GP - 1);
        Wt[idx] = (g < 400) ? W_ih[g * IN_SZ + k] : 0.f;
    }
    if (idx < GP) bias[idx] = (idx < 400) ? (b_ih[idx] + b_hh[idx]) : 0.f;
    if (idx < 400 * KP) {
        int g = idx / KP;
        int k = idx - g * KP;
        Whp[idx] = (k < H_SZ) ? W_hh[g * H_SZ + k] : 0.f;
    }
}

// ---------------- input projection GEMM (pk_fma packed) ----------------
__global__ __launch_bounds__(256, 4) void xproj_kernel(
    const float* __restrict__ x, const float* __restrict__ Wt,
    const float* __restrict__ bias, float* __restrict__ xg,
    int t0, int Tlen) {
    __shared__ __align__(16) float xTc[50][68];
    __shared__ __align__(16) float4 LW[50][32];

    const int tid = threadIdx.x;
    const int gblk = blockIdx.x;
    const int tbase = t0 + blockIdx.y * 64;
    const int b = blockIdx.z;
    const int gt = tid & 15;
    const int tt = tid >> 4;

    v2f acc[4][4];
#pragma unroll
    for (int r = 0; r < 4; ++r)
#pragma unroll
        for (int h = 0; h < 4; ++h) { acc[r][h].x = 0.f; acc[r][h].y = 0.f; }

    const float2* x2 = (const float2*)x;
    const float4* Wt4 = (const float4*)Wt;

    for (int kc = 0; kc < 4; ++kc) {
        for (int idx = tid; idx < 64 * 25; idx += 256) {
            int row = idx / 25, c2 = idx % 25;
            float2 v = x2[(size_t)(b * T_TOTAL + tbase + row) * (IN_SZ / 2) + kc * 25 + c2];
            xTc[c2 * 2][row] = v.x;
            xTc[c2 * 2 + 1][row] = v.y;
        }
        for (int idx = tid; idx < 50 * 32; idx += 256) {
            int k = idx >> 5, c = idx & 31;
            LW[k][c] = Wt4[(size_t)(kc * 50 + k) * (GP / 4) + gblk * 32 + c];
        }
        __syncthreads();

#pragma unroll 5
        for (int k = 0; k < 50; ++k) {
            float4 xv = *(const float4*)&xTc[k][tt * 4];
            float4 w0 = LW[k][gt];
            float4 w1 = LW[k][16 + gt];
            v2f wv[4];
            wv[0].x = w0.x; wv[0].y = w0.y; wv[1].x = w0.z; wv[1].y = w0.w;
            wv[2].x = w1.x; wv[2].y = w1.y; wv[3].x = w1.z; wv[3].y = w1.w;
            float xa[4] = {xv.x, xv.y, xv.z, xv.w};
#pragma unroll
            for (int tr = 0; tr < 4; ++tr) {
                v2f xs; xs.x = xa[tr]; xs.y = xa[tr];
#pragma unroll
                for (int h = 0; h < 4; ++h)
                    acc[tr][h] = __builtin_elementwise_fma(xs, wv[h], acc[tr][h]);
            }
        }
        __syncthreads();
    }

    const float4* bias4 = (const float4*)bias;
    float4 b0 = bias4[gblk * 32 + gt];
    float4 b1 = bias4[gblk * 32 + 16 + gt];
    float4* o4 = (float4*)xg;
#pragma unroll
    for (int tr = 0; tr < 4; ++tr) {
        int trow = (tbase - t0) + tt * 4 + tr;
        size_t o = (size_t)(b * Tlen + trow) * (GP / 4) + gblk * 32;
        float4 v0 = make_float4(acc[tr][0].x + b0.x, acc[tr][0].y + b0.y,
                                acc[tr][1].x + b0.z, acc[tr][1].y + b0.w);
        float4 v1 = make_float4(acc[tr][2].x + b1.x, acc[tr][2].y + b1.y,
                                acc[tr][3].x + b1.z, acc[tr][3].y + b1.w);
        o4[o + gt] = v0;
        o4[o + 16 + gt] = v1;
    }
}

// ---------------- recurrence: one WG (512 thr) per batch ----------------
__global__ __attribute__((amdgpu_flat_work_group_size(512, 512), amdgpu_waves_per_eu(2, 2)))
void lstm_kernel(
    const float* __restrict__ xg, const float* __restrict__ Whp,
    float* __restrict__ hstate, float* __restrict__ cstate,
    float* __restrict__ out, int Tlen, int first, int last) {
    __shared__ __align__(16) float hlds[2][KP];  // double-buffered h[100] + pad

    const int b = blockIdx.x;
    const int tid = threadIdx.x;
    const int q = tid >> 2;
    const int s4 = tid & 3;
    const bool active = (q < H_SZ);
    const int qc = active ? q : (H_SZ - 1);  // clamped: inactive lanes mirror q=99

    // 4 gate quarter-rows: 4 x 14 v2f = 112 regs, resident.
    v2f w[4][14];
    if (active) {
        const v2f* W2 = (const v2f*)Whp;
#pragma unroll
        for (int g = 0; g < 4; ++g) {
            const v2f* row = W2 + (size_t)(g * H_SZ + q) * (KP / 2) + s4 * 14;
#pragma unroll
            for (int m = 0; m < 14; ++m) w[g][m] = row[m];
        }
    } else {
#pragma unroll
        for (int g = 0; g < 4; ++g)
#pragma unroll
            for (int m = 0; m < 14; ++m) { w[g][m].x = 0.f; w[g][m].y = 0.f; }
    }

    // xg injection selector: lane s4 contributes gate s4's x before the butterfly
    float sf[4];
#pragma unroll
    for (int g = 0; g < 4; ++g) sf[g] = (s4 == g) ? 1.f : 0.f;

    float c = 0.f;
    if (active) c = first ? 0.f : cstate[b * H_SZ + q];
    if (tid < KP) hlds[0][tid] = (tid < H_SZ) ? (first ? 0.f : hstate[b * H_SZ + tid]) : 0.f;
    if (tid < KP - H_SZ) hlds[1][H_SZ + tid] = 0.f;  // zero pad of buffer 1
    __syncthreads();

    // per-thread xg pointer (clamped for inactive lanes -> UNCONDITIONAL loads)
    const float* xp = xg + (size_t)b * Tlen * GP + (size_t)(s4 * H_SZ + qc);

    // depth-4 register pipeline; all loads unconditional (buffer has 4-step slack)
    float x0 = xp[0 * GP];
    float x1 = xp[1 * GP];
    float x2 = xp[2 * GP];
    float x3 = xp[3 * GP];
    const float* xq = xp + 4 * GP;  // reload cursor: step t+4 for body 0

    float hval = 0.f;

    // One LSTM step: consume pipeline reg XB, read hlds[RB], write hlds[WB],
    // reload XB from xq + KOFF*GP (step t+4). Unconditional load -> counted
    // vmcnt wait at consumption 4 steps later, zero per-step stall.
#define LSTM_STEP(XB, RB, WB, KOFF)                                            \
    {                                                                          \
        const float4* hb4 = (const float4*)&hlds[RB][s4 * 28];                 \
        v2f a0[4], a1[4];                                                      \
        _Pragma("unroll") for (int g = 0; g < 4; ++g) {                        \
            a0[g].x = 0.f; a0[g].y = 0.f;                                      \
            a1[g].x = 0.f; a1[g].y = 0.f;                                      \
        }                                                                      \
        _Pragma("unroll") for (int m = 0; m < 7; ++m) {                        \
            float4 h4 = hb4[m];                                                \
            v2f hlo; hlo.x = h4.x; hlo.y = h4.y;                               \
            v2f hhi; hhi.x = h4.z; hhi.y = h4.w;                               \
            _Pragma("unroll") for (int g = 0; g < 4; ++g) {                    \
                a0[g] = __builtin_elementwise_fma(hlo, w[g][2 * m], a0[g]);    \
                a1[g] = __builtin_elementwise_fma(hhi, w[g][2 * m + 1], a1[g]);\
            }                                                                  \
        }                                                                      \
        float d[4];                                                            \
        _Pragma("unroll") for (int g = 0; g < 4; ++g) {                        \
            v2f sv = a0[g] + a1[g];                                            \
            float p = sv.x + sv.y;                                             \
            p = __builtin_fmaf(sf[g], XB, p);                                  \
            float p1 = p + QSWAP(p, 0xB1);                                     \
            d[g] = p1 + QSWAP(p1, 0x4E);                                       \
        }                                                                      \
        XB = xq[(KOFF) * GP];                                                  \
        float ai = sigf(d[0]);                                                 \
        float af = sigf(d[1]);                                                 \
        float ag = __builtin_fmaf(sigf(2.f * d[2]), 2.f, -1.f);                \
        float ao = sigf(d[3]);                                                 \
        c = __builtin_fmaf(af, c, ai * ag);                                    \
        float tc = __builtin_fmaf(sigf(2.f * c), 2.f, -1.f);                   \
        hval = ao * tc;                                                        \
        if (active && s4 == 0) hlds[WB][q] = hval;                             \
        __syncthreads();                                                       \
    }

    for (int tl = 0; tl < Tlen; tl += 4) {
        LSTM_STEP(x0, 0, 1, 0);
        LSTM_STEP(x1, 1, 0, 1);
        LSTM_STEP(x2, 0, 1, 2);
        LSTM_STEP(x3, 1, 0, 3);
        xq += 4 * GP;
    }
#undef LSTM_STEP

    if (active && s4 == 0) {
        hstate[b * H_SZ + q] = hval;
        cstate[b * H_SZ + q] = c;
        if (last) out[b * H_SZ + q] = hval;
    }
}

// ---------------- host ----------------
extern "C" void kernel_launch(void* const* d_in, const int* in_sizes, int n_in,
                              void* d_out, int out_size, void* d_ws, size_t ws_size,
                              hipStream_t stream) {
    const float* x    = (const float*)d_in[0];
    const float* W_ih = (const float*)d_in[1];
    const float* W_hh = (const float*)d_in[2];
    const float* b_ih = (const float*)d_in[3];
    const float* b_hh = (const float*)d_in[4];
    float* out = (float*)d_out;

    char* ws = (char*)d_ws;
    float* Wt     = (float*)(ws);            // 200*512*4      = 409600
    float* bias   = (float*)(ws + 409600);   // 512*4          = 2048
    float* Whp    = (float*)(ws + 411648);   // 400*112*4      = 179200
    float* hstate = (float*)(ws + 590848);   // 64*100*4       = 25600
    float* cstate = (float*)(ws + 616448);   // 64*100*4       = 25600
    float* xgbuf  = (float*)(ws + 642048);

    // reserve 4*GP floats (8192 B) of slack after xg for the unconditional
    // depth-4 pipeline overread of the last batch
    size_t cap = (ws_size > 642048 + 8192) ? (ws_size - 642048 - 8192) : 0;
    long long tcmax = (long long)(cap / ((size_t)B_SZ * GP * 4));
    int Tc = (int)((tcmax / 64) * 64);
    if (Tc > T_TOTAL) Tc = T_TOTAL;
    if (Tc < 64) Tc = 64;

    prep_kernel<<<400, 256, 0, stream>>>(W_ih, W_hh, b_ih, b_hh, Wt, bias, Whp);

    for (int t0 = 0; t0 < T_TOTAL; t0 += Tc) {
        int Tlen = T_TOTAL - t0;
        if (Tlen > Tc) Tlen = Tc;
        xproj_kernel<<<dim3(4, Tlen / 64, B_SZ), 256, 0, stream>>>(x, Wt, bias, xgbuf, t0, Tlen);
        lstm_kernel<<<B_SZ, 512, 0, stream>>>(xgbuf, Whp, hstate, cstate, out,
                                              Tlen, t0 == 0 ? 1 : 0,
                                              (t0 + Tlen) == T_TOTAL ? 1 : 0);
    }
}

// Round 6
// 1362.707 us; speedup vs baseline: 1.5024x; 1.1486x over previous
//
#include <hip/hip_runtime.h>
#include <math.h>

// LSTM: B=64, T=2048, I=200, H=100. Output h_T [64,100] fp32.
// FUSED persistent producer/consumer kernel (this round's change):
//   - blocks 0..63   : R5's lstm recurrence, math byte-identical, looping over
//                      chunks of TC steps from a ring of NB xg buffers.
//   - blocks 64..255 : 192 producer blocks computing xproj (input projection)
//                      one chunk ahead into the ring.  xproj ran serially
//                      before (~440us of 1565us); now hidden under the 1124us
//                      recurrence (the chip was 75% idle during lstm).
//   Sync: device-scope atomics on done[]/freed[] counters + __threadfence()
//   (release after producer stores, acquire after consumer poll) per the
//   XCD-non-coherence rules. Exactly 256 blocks x 512thr = 1 block/CU, all
//   co-resident by construction -> no dispatch deadlock.

#define T_TOTAL 2048
#define B_SZ 64
#define IN_SZ 200
#define H_SZ 100
#define GP 512   // padded gate dim (4*H=400 -> 512)
#define KP 112   // padded hidden dim for Whh rows (100 -> 112, quarter = 28)
#define NPROD 192
#define NBLK 256

typedef float v2f __attribute__((ext_vector_type(2)));

__device__ __forceinline__ float sigf(float x) {
    return __builtin_amdgcn_rcpf(1.f + __expf(-x));
}

#define QSWAP(x, ctrl) \
    __int_as_float(__builtin_amdgcn_mov_dpp(__float_as_int(x), ctrl, 0xF, 0xF, true))

// ---------------- prep ----------------
__global__ void prep_kernel(const float* __restrict__ W_ih,
                            const float* __restrict__ W_hh,
                            const float* __restrict__ b_ih,
                            const float* __restrict__ b_hh,
                            float* __restrict__ Wt,
                            float* __restrict__ bias,
                            float* __restrict__ Whp,
                            unsigned int* __restrict__ sync) {
    int idx = blockIdx.x * 256 + threadIdx.x;
    if (idx < IN_SZ * GP) {
        int k = idx >> 9;
        int g = idx & (GP - 1);
        Wt[idx] = (g < 400) ? W_ih[g * IN_SZ + k] : 0.f;
    }
    if (idx < GP) bias[idx] = (idx < 400) ? (b_ih[idx] + b_hh[idx]) : 0.f;
    if (idx < 400 * KP) {
        int g = idx / KP;
        int k = idx - g * KP;
        Whp[idx] = (k < H_SZ) ? W_hh[g * H_SZ + k] : 0.f;
    }
    if (idx < 64) sync[idx] = 0u;  // done[0..31], freed[0..31]
}

// ---------------- fused persistent kernel ----------------
__global__ __attribute__((amdgpu_flat_work_group_size(512, 512), amdgpu_waves_per_eu(2, 2)))
void fused_kernel(const float* __restrict__ x,
                  const float* __restrict__ Wt,
                  const float* __restrict__ bias,
                  const float* __restrict__ Whp,
                  float* __restrict__ xg,   // NB ring slots, + 8KB slack after
                  float* __restrict__ out,
                  unsigned int* __restrict__ sync,
                  int TC, int NB, int nch) {
    __shared__ __align__(16) float hlds[2][KP];       // consumer
    __shared__ __align__(16) float xTc[2][50][68];    // producer
    __shared__ __align__(16) float4 LW[50][32];       // producer

    const int bid = blockIdx.x;
    const int tid = threadIdx.x;
    unsigned int* done = sync;
    unsigned int* freed = sync + 32;
    const size_t slot_sz = (size_t)B_SZ * TC * GP;

    if (bid < B_SZ) {
        // ================= consumer: LSTM recurrence (R5 body) =================
        const int b = bid;
        const int q = tid >> 2;
        const int s4 = tid & 3;
        const bool active = (q < H_SZ);
        const int qc = active ? q : (H_SZ - 1);

        v2f w[4][14];
        if (active) {
            const v2f* W2 = (const v2f*)Whp;
#pragma unroll
            for (int g = 0; g < 4; ++g) {
                const v2f* row = W2 + (size_t)(g * H_SZ + q) * (KP / 2) + s4 * 14;
#pragma unroll
                for (int m = 0; m < 14; ++m) w[g][m] = row[m];
            }
        } else {
#pragma unroll
            for (int g = 0; g < 4; ++g)
#pragma unroll
                for (int m = 0; m < 14; ++m) { w[g][m].x = 0.f; w[g][m].y = 0.f; }
        }

        float sf[4];
#pragma unroll
        for (int g = 0; g < 4; ++g) sf[g] = (s4 == g) ? 1.f : 0.f;

        float c = 0.f;
        if (tid < KP) hlds[0][tid] = 0.f;
        if (tid < KP - H_SZ) hlds[1][H_SZ + tid] = 0.f;
        __syncthreads();

        const size_t lane_off = (size_t)(s4 * H_SZ + qc);
        float hval = 0.f;

#define LSTM_STEP(XB, RB, WB, KOFF)                                            \
    {                                                                          \
        const float4* hb4 = (const float4*)&hlds[RB][s4 * 28];                 \
        v2f a0[4], a1[4];                                                      \
        _Pragma("unroll") for (int g = 0; g < 4; ++g) {                        \
            a0[g].x = 0.f; a0[g].y = 0.f;                                      \
            a1[g].x = 0.f; a1[g].y = 0.f;                                      \
        }                                                                      \
        _Pragma("unroll") for (int m = 0; m < 7; ++m) {                        \
            float4 h4 = hb4[m];                                                \
            v2f hlo; hlo.x = h4.x; hlo.y = h4.y;                               \
            v2f hhi; hhi.x = h4.z; hhi.y = h4.w;                               \
            _Pragma("unroll") for (int g = 0; g < 4; ++g) {                    \
                a0[g] = __builtin_elementwise_fma(hlo, w[g][2 * m], a0[g]);    \
                a1[g] = __builtin_elementwise_fma(hhi, w[g][2 * m + 1], a1[g]);\
            }                                                                  \
        }                                                                      \
        float d[4];                                                            \
        _Pragma("unroll") for (int g = 0; g < 4; ++g) {                        \
            v2f sv = a0[g] + a1[g];                                            \
            float p = sv.x + sv.y;                                             \
            p = __builtin_fmaf(sf[g], XB, p);                                  \
            float p1 = p + QSWAP(p, 0xB1);                                     \
            d[g] = p1 + QSWAP(p1, 0x4E);                                       \
        }                                                                      \
        XB = xq[(KOFF) * GP];                                                  \
        float ai = sigf(d[0]);                                                 \
        float af = sigf(d[1]);                                                 \
        float ag = __builtin_fmaf(sigf(2.f * d[2]), 2.f, -1.f);                \
        float ao = sigf(d[3]);                                                 \
        c = __builtin_fmaf(af, c, ai * ag);                                    \
        float tc = __builtin_fmaf(sigf(2.f * c), 2.f, -1.f);                   \
        hval = ao * tc;                                                        \
        if (active && s4 == 0) hlds[WB][q] = hval;                             \
        __syncthreads();                                                       \
    }

        for (int k = 0; k < nch; ++k) {
            if (tid == 0) {
                while (atomicAdd(&done[k], 0u) < (unsigned)NPROD)
                    __builtin_amdgcn_s_sleep(8);
                __threadfence();  // acquire: invalidate stale L1/L2 lines of this slot
            }
            __syncthreads();

            const float* xp = xg + (size_t)(k % NB) * slot_sz + (size_t)b * TC * GP + lane_off;
            float xr0 = xp[0 * GP];
            float xr1 = xp[1 * GP];
            float xr2 = xp[2 * GP];
            float xr3 = xp[3 * GP];
            const float* xq = xp + 4 * GP;

            for (int tl = 0; tl < TC; tl += 4) {
                LSTM_STEP(xr0, 0, 1, 0);
                LSTM_STEP(xr1, 1, 0, 1);
                LSTM_STEP(xr2, 0, 1, 2);
                LSTM_STEP(xr3, 1, 0, 3);
                xq += 4 * GP;
            }
            // last step's __syncthreads passed: all lanes done consuming slot
            if (tid == 0) atomicAdd(&freed[k], 1u);
        }
#undef LSTM_STEP

        if (active && s4 == 0) out[b * H_SZ + q] = hval;

    } else {
        // ================= producer: xproj, one chunk ahead =================
        const int pid = bid - B_SZ;     // 0..191
        const int h = tid >> 8;         // half: rows [h*64, h*64+64)
        const int t2 = tid & 255;
        const int gt = t2 & 15;
        const int tt = t2 >> 4;
        const int TPB = TC >> 7;        // 128-row tiles per batch per chunk
        const int njobs = B_SZ * TPB * 4;
        const float2* x2 = (const float2*)x;
        const float4* Wt4 = (const float4*)Wt;
        const float4* bias4 = (const float4*)bias;

        for (int k = 0; k < nch; ++k) {
            if (k >= NB) {
                if (tid == 0)
                    while (atomicAdd(&freed[k - NB], 0u) < (unsigned)B_SZ)
                        __builtin_amdgcn_s_sleep(8);
                __syncthreads();
            }
            float* slot = xg + (size_t)(k % NB) * slot_sz;
            float4* slot4 = (float4*)slot;

            for (int job = pid; job < njobs; job += NPROD) {
                const int b = job / (TPB * 4);
                const int r = job - b * (TPB * 4);
                const int tj = r >> 2;
                const int gblk = r & 3;
                const int tl0 = tj * 128 + h * 64;       // local t base (this half)
                const int ta0 = k * TC + tl0;            // absolute t base

                v2f acc[4][4];
#pragma unroll
                for (int tr = 0; tr < 4; ++tr)
#pragma unroll
                    for (int hh = 0; hh < 4; ++hh) { acc[tr][hh].x = 0.f; acc[tr][hh].y = 0.f; }

                for (int kc = 0; kc < 4; ++kc) {
                    for (int idx = t2; idx < 64 * 25; idx += 256) {
                        int row = idx / 25, c2 = idx % 25;
                        float2 v = x2[(size_t)(b * T_TOTAL + ta0 + row) * (IN_SZ / 2) + kc * 25 + c2];
                        xTc[h][c2 * 2][row] = v.x;
                        xTc[h][c2 * 2 + 1][row] = v.y;
                    }
                    for (int idx = tid; idx < 50 * 32; idx += 512) {
                        int kk = idx >> 5, cc = idx & 31;
                        LW[kk][cc] = Wt4[(size_t)(kc * 50 + kk) * (GP / 4) + gblk * 32 + cc];
                    }
                    __syncthreads();

#pragma unroll 5
                    for (int kk = 0; kk < 50; ++kk) {
                        float4 xv = *(const float4*)&xTc[h][kk][tt * 4];
                        float4 w0 = LW[kk][gt];
                        float4 w1 = LW[kk][16 + gt];
                        v2f wv[4];
                        wv[0].x = w0.x; wv[0].y = w0.y; wv[1].x = w0.z; wv[1].y = w0.w;
                        wv[2].x = w1.x; wv[2].y = w1.y; wv[3].x = w1.z; wv[3].y = w1.w;
                        float xa[4] = {xv.x, xv.y, xv.z, xv.w};
#pragma unroll
                        for (int tr = 0; tr < 4; ++tr) {
                            v2f xs; xs.x = xa[tr]; xs.y = xa[tr];
#pragma unroll
                            for (int hh = 0; hh < 4; ++hh)
                                acc[tr][hh] = __builtin_elementwise_fma(xs, wv[hh], acc[tr][hh]);
                        }
                    }
                    __syncthreads();
                }

                float4 b0 = bias4[gblk * 32 + gt];
                float4 b1 = bias4[gblk * 32 + 16 + gt];
#pragma unroll
                for (int tr = 0; tr < 4; ++tr) {
                    int trow = tl0 + tt * 4 + tr;
                    size_t o = (size_t)(b * TC + trow) * (GP / 4) + gblk * 32;
                    float4 v0 = make_float4(acc[tr][0].x + b0.x, acc[tr][0].y + b0.y,
                                            acc[tr][1].x + b0.z, acc[tr][1].y + b0.w);
                    float4 v1 = make_float4(acc[tr][2].x + b1.x, acc[tr][2].y + b1.y,
                                            acc[tr][3].x + b1.z, acc[tr][3].y + b1.w);
                    slot4[o + gt] = v0;
                    slot4[o + 16 + gt] = v1;
                }
            }
            __syncthreads();  // drains all waves' stores (vmcnt) before signal
            if (tid == 0) {
                __threadfence();         // release: writes visible device-wide
                atomicAdd(&done[k], 1u);
            }
        }
    }
}

// ---------------- host ----------------
extern "C" void kernel_launch(void* const* d_in, const int* in_sizes, int n_in,
                              void* d_out, int out_size, void* d_ws, size_t ws_size,
                              hipStream_t stream) {
    const float* x    = (const float*)d_in[0];
    const float* W_ih = (const float*)d_in[1];
    const float* W_hh = (const float*)d_in[2];
    const float* b_ih = (const float*)d_in[3];
    const float* b_hh = (const float*)d_in[4];
    float* out = (float*)d_out;

    char* ws = (char*)d_ws;
    float* Wt           = (float*)(ws);            // 200*512*4  = 409600
    float* bias         = (float*)(ws + 409600);   // 512*4      = 2048
    float* Whp          = (float*)(ws + 411648);   // 400*112*4  = 179200 -> 590848
    unsigned int* sync  = (unsigned int*)(ws + 590848);  // 64*4 = 256 -> 591104
    float* xgbuf        = (float*)(ws + 593920);   // ring buffers + 8KB slack

    // pick chunk size / ring depth from workspace (prefer overlap: NB=2)
    size_t avail = (ws_size > 593920 + 8192) ? (ws_size - 593920 - 8192) : 0;
    int TC, NB;
    if (avail >= 2ull * B_SZ * 256 * GP * 4)      { TC = 256; NB = 2; }
    else if (avail >= 2ull * B_SZ * 128 * GP * 4) { TC = 128; NB = 2; }
    else                                          { TC = 128; NB = 1; }  // blind floor
    int nch = T_TOTAL / TC;

    prep_kernel<<<400, 256, 0, stream>>>(W_ih, W_hh, b_ih, b_hh, Wt, bias, Whp, sync);
    fused_kernel<<<NBLK, 512, 0, stream>>>(x, Wt, bias, Whp, xgbuf, out, sync,
                                           TC, NB, nch);
}

// Round 7
// 1260.203 us; speedup vs baseline: 1.6246x; 1.0813x over previous
//
#include <hip/hip_runtime.h>
#include <math.h>

// LSTM: B=64, T=2048, I=200, H=100. Output h_T [64,100] fp32.
// FUSED persistent producer/consumer kernel:
//   - blocks 0..63   : LSTM recurrence, chunks of TC steps from a ring of NB
//                      xg buffers.
//   - blocks 64..255 : 192 producer blocks computing xproj one chunk ahead.
//   Sync: device-scope atomics on done[]/freed[] + __threadfence().
// ROUND 7 change (consumer step only): cut issue count ~35%.
//   * transposed quad reduce (6 cndmask + 3 DPP + 3 add) -> lane s4 ends with
//     ONLY its own gate's complete dot (old butterfly computed all 4 dots on
//     every lane: 8 DPP + 8 add + 4 fma).
//   * own-gate activation: 1 sigf/thread (was 4) with per-lane tanh constants,
//     then 4 quad-broadcast DPPs redistribute activated i,f,g,o (R0's trick).
//   * accumulator zero-init replaced by pk_mul first iteration.
// Producers, ring sync, depth-4 xg pipeline: identical to round 6.

#define T_TOTAL 2048
#define B_SZ 64
#define IN_SZ 200
#define H_SZ 100
#define GP 512   // padded gate dim (4*H=400 -> 512)
#define KP 112   // padded hidden dim for Whh rows (100 -> 112, quarter = 28)
#define NPROD 192
#define NBLK 256

typedef float v2f __attribute__((ext_vector_type(2)));

__device__ __forceinline__ float sigf(float x) {
    return __builtin_amdgcn_rcpf(1.f + __expf(-x));
}

// quad_perm DPP move (bound_ctrl=true)
#define QSWAP(x, ctrl) \
    __int_as_float(__builtin_amdgcn_mov_dpp(__float_as_int(x), ctrl, 0xF, 0xF, true))
// broadcast lane (ctrl) of each quad to all 4 lanes
#define QBCAST(x, ctrl) QSWAP(x, ctrl)

// ---------------- prep ----------------
__global__ void prep_kernel(const float* __restrict__ W_ih,
                            const float* __restrict__ W_hh,
                            const float* __restrict__ b_ih,
                            const float* __restrict__ b_hh,
                            float* __restrict__ Wt,
                            float* __restrict__ bias,
                            float* __restrict__ Whp,
                            unsigned int* __restrict__ sync) {
    int idx = blockIdx.x * 256 + threadIdx.x;
    if (idx < IN_SZ * GP) {
        int k = idx >> 9;
        int g = idx & (GP - 1);
        Wt[idx] = (g < 400) ? W_ih[g * IN_SZ + k] : 0.f;
    }
    if (idx < GP) bias[idx] = (idx < 400) ? (b_ih[idx] + b_hh[idx]) : 0.f;
    if (idx < 400 * KP) {
        int g = idx / KP;
        int k = idx - g * KP;
        Whp[idx] = (k < H_SZ) ? W_hh[g * H_SZ + k] : 0.f;
    }
    if (idx < 64) sync[idx] = 0u;  // done[0..31], freed[0..31]
}

// ---------------- fused persistent kernel ----------------
__global__ __attribute__((amdgpu_flat_work_group_size(512, 512), amdgpu_waves_per_eu(2, 2)))
void fused_kernel(const float* __restrict__ x,
                  const float* __restrict__ Wt,
                  const float* __restrict__ bias,
                  const float* __restrict__ Whp,
                  float* __restrict__ xg,   // NB ring slots, + 8KB slack after
                  float* __restrict__ out,
                  unsigned int* __restrict__ sync,
                  int TC, int NB, int nch) {
    __shared__ __align__(16) float hlds[2][KP];       // consumer
    __shared__ __align__(16) float xTc[2][50][68];    // producer
    __shared__ __align__(16) float4 LW[50][32];       // producer

    const int bid = blockIdx.x;
    const int tid = threadIdx.x;
    unsigned int* done = sync;
    unsigned int* freed = sync + 32;
    const size_t slot_sz = (size_t)B_SZ * TC * GP;

    if (bid < B_SZ) {
        // ================= consumer: LSTM recurrence =================
        const int b = bid;
        const int q = tid >> 2;
        const int s4 = tid & 3;
        const bool active = (q < H_SZ);
        const int qc = active ? q : (H_SZ - 1);
        const bool o1 = (s4 & 1) != 0;
        const bool o2 = (s4 & 2) != 0;
        // own-gate activation constants: s4==2 is the tanh gate (g)
        const float asc  = (s4 == 2) ? 2.f : 1.f;
        const float amul = (s4 == 2) ? 2.f : 1.f;
        const float aadd = (s4 == 2) ? -1.f : 0.f;

        v2f w[4][14];
        if (active) {
            const v2f* W2 = (const v2f*)Whp;
#pragma unroll
            for (int g = 0; g < 4; ++g) {
                const v2f* row = W2 + (size_t)(g * H_SZ + q) * (KP / 2) + s4 * 14;
#pragma unroll
                for (int m = 0; m < 14; ++m) w[g][m] = row[m];
            }
        } else {
#pragma unroll
            for (int g = 0; g < 4; ++g)
#pragma unroll
                for (int m = 0; m < 14; ++m) { w[g][m].x = 0.f; w[g][m].y = 0.f; }
        }

        float c = 0.f;
        if (tid < KP) hlds[0][tid] = 0.f;
        if (tid < KP - H_SZ) hlds[1][H_SZ + tid] = 0.f;
        __syncthreads();

        const size_t lane_off = (size_t)(s4 * H_SZ + qc);
        float hval = 0.f;

        // One LSTM step. Transposed quad reduce (verified lane-by-lane):
        //   p[g] = partial dot of gate g over quarter s4 (this lane).
        //   pair stage (0<->1, 2<->3 via quad_perm [1,0,3,2]):
        //     r01(l0)=gate0 sum q{0,1}, (l1)=gate1 q{0,1}, (l2)=gate0 q{2,3}, (l3)=gate1 q{2,3}
        //     r23(l0)=gate2 q{0,1}, (l1)=gate3 q{0,1}, (l2)=gate2 q{2,3}, (l3)=gate3 q{2,3}
        //   cross stage (0<->2, 1<->3 via [2,3,0,1]):
        //     dwn(l) = full dot of gate l  (+ own xg, which lane l loads for gate l)
        //   Then lane l activates ONLY gate l; 4 quad-broadcasts redistribute.
#define LSTM_STEP(XB, RB, WB, KOFF)                                            \
    {                                                                          \
        const float4* hb4 = (const float4*)&hlds[RB][s4 * 28];                 \
        float4 h4 = hb4[0];                                                    \
        v2f hlo; hlo.x = h4.x; hlo.y = h4.y;                                   \
        v2f hhi; hhi.x = h4.z; hhi.y = h4.w;                                   \
        v2f a0[4], a1[4];                                                      \
        _Pragma("unroll") for (int g = 0; g < 4; ++g) {                        \
            a0[g] = hlo * w[g][0];                                             \
            a1[g] = hhi * w[g][1];                                             \
        }                                                                      \
        _Pragma("unroll") for (int m = 1; m < 7; ++m) {                        \
            h4 = hb4[m];                                                       \
            hlo.x = h4.x; hlo.y = h4.y;                                        \
            hhi.x = h4.z; hhi.y = h4.w;                                        \
            _Pragma("unroll") for (int g = 0; g < 4; ++g) {                    \
                a0[g] = __builtin_elementwise_fma(hlo, w[g][2 * m], a0[g]);    \
                a1[g] = __builtin_elementwise_fma(hhi, w[g][2 * m + 1], a1[g]);\
            }                                                                  \
        }                                                                      \
        float p[4];                                                            \
        _Pragma("unroll") for (int g = 0; g < 4; ++g) {                        \
            v2f sv = a0[g] + a1[g];                                            \
            p[g] = sv.x + sv.y;                                                \
        }                                                                      \
        float e01 = o1 ? p[0] : p[1];                                          \
        float r01 = (o1 ? p[1] : p[0]) + QSWAP(e01, 0xB1);                     \
        float e23 = o1 ? p[2] : p[3];                                          \
        float r23 = (o1 ? p[3] : p[2]) + QSWAP(e23, 0xB1);                     \
        float ecx = o2 ? r01 : r23;                                            \
        float dwn = (o2 ? r23 : r01) + QSWAP(ecx, 0x4E) + XB;                  \
        XB = xq[(KOFF) * GP];                                                  \
        float act = __builtin_fmaf(sigf(asc * dwn), amul, aadd);               \
        float vi = QBCAST(act, 0x00);                                          \
        float vf = QBCAST(act, 0x55);                                          \
        float vg = QBCAST(act, 0xAA);                                          \
        float vo = QBCAST(act, 0xFF);                                          \
        c = __builtin_fmaf(vf, c, vi * vg);                                    \
        float tcv = __builtin_fmaf(sigf(2.f * c), 2.f, -1.f);                  \
        hval = vo * tcv;                                                       \
        if (active && s4 == 0) hlds[WB][q] = hval;                             \
        __syncthreads();                                                       \
    }

        for (int k = 0; k < nch; ++k) {
            if (tid == 0) {
                while (atomicAdd(&done[k], 0u) < (unsigned)NPROD)
                    __builtin_amdgcn_s_sleep(8);
                __threadfence();  // acquire
            }
            __syncthreads();

            const float* xp = xg + (size_t)(k % NB) * slot_sz + (size_t)b * TC * GP + lane_off;
            float xr0 = xp[0 * GP];
            float xr1 = xp[1 * GP];
            float xr2 = xp[2 * GP];
            float xr3 = xp[3 * GP];
            const float* xq = xp + 4 * GP;

            for (int tl = 0; tl < TC; tl += 4) {
                LSTM_STEP(xr0, 0, 1, 0);
                LSTM_STEP(xr1, 1, 0, 1);
                LSTM_STEP(xr2, 0, 1, 2);
                LSTM_STEP(xr3, 1, 0, 3);
                xq += 4 * GP;
            }
            if (tid == 0) atomicAdd(&freed[k], 1u);
        }
#undef LSTM_STEP

        if (active && s4 == 0) out[b * H_SZ + q] = hval;

    } else {
        // ================= producer: xproj, one chunk ahead =================
        const int pid = bid - B_SZ;     // 0..191
        const int h = tid >> 8;         // half: rows [h*64, h*64+64)
        const int t2 = tid & 255;
        const int gt = t2 & 15;
        const int tt = t2 >> 4;
        const int TPB = TC >> 7;        // 128-row tiles per batch per chunk
        const int njobs = B_SZ * TPB * 4;
        const float2* x2 = (const float2*)x;
        const float4* Wt4 = (const float4*)Wt;
        const float4* bias4 = (const float4*)bias;

        for (int k = 0; k < nch; ++k) {
            if (k >= NB) {
                if (tid == 0)
                    while (atomicAdd(&freed[k - NB], 0u) < (unsigned)B_SZ)
                        __builtin_amdgcn_s_sleep(8);
                __syncthreads();
            }
            float* slot = xg + (size_t)(k % NB) * slot_sz;
            float4* slot4 = (float4*)slot;

            for (int job = pid; job < njobs; job += NPROD) {
                const int b = job / (TPB * 4);
                const int r = job - b * (TPB * 4);
                const int tj = r >> 2;
                const int gblk = r & 3;
                const int tl0 = tj * 128 + h * 64;       // local t base (this half)
                const int ta0 = k * TC + tl0;            // absolute t base

                v2f acc[4][4];
#pragma unroll
                for (int tr = 0; tr < 4; ++tr)
#pragma unroll
                    for (int hh = 0; hh < 4; ++hh) { acc[tr][hh].x = 0.f; acc[tr][hh].y = 0.f; }

                for (int kc = 0; kc < 4; ++kc) {
                    for (int idx = t2; idx < 64 * 25; idx += 256) {
                        int row = idx / 25, c2 = idx % 25;
                        float2 v = x2[(size_t)(b * T_TOTAL + ta0 + row) * (IN_SZ / 2) + kc * 25 + c2];
                        xTc[h][c2 * 2][row] = v.x;
                        xTc[h][c2 * 2 + 1][row] = v.y;
                    }
                    for (int idx = tid; idx < 50 * 32; idx += 512) {
                        int kk = idx >> 5, cc = idx & 31;
                        LW[kk][cc] = Wt4[(size_t)(kc * 50 + kk) * (GP / 4) + gblk * 32 + cc];
                    }
                    __syncthreads();

#pragma unroll 5
                    for (int kk = 0; kk < 50; ++kk) {
                        float4 xv = *(const float4*)&xTc[h][kk][tt * 4];
                        float4 w0 = LW[kk][gt];
                        float4 w1 = LW[kk][16 + gt];
                        v2f wv[4];
                        wv[0].x = w0.x; wv[0].y = w0.y; wv[1].x = w0.z; wv[1].y = w0.w;
                        wv[2].x = w1.x; wv[2].y = w1.y; wv[3].x = w1.z; wv[3].y = w1.w;
                        float xa[4] = {xv.x, xv.y, xv.z, xv.w};
#pragma unroll
                        for (int tr = 0; tr < 4; ++tr) {
                            v2f xs; xs.x = xa[tr]; xs.y = xa[tr];
#pragma unroll
                            for (int hh = 0; hh < 4; ++hh)
                                acc[tr][hh] = __builtin_elementwise_fma(xs, wv[hh], acc[tr][hh]);
                        }
                    }
                    __syncthreads();
                }

                float4 b0 = bias4[gblk * 32 + gt];
                float4 b1 = bias4[gblk * 32 + 16 + gt];
#pragma unroll
                for (int tr = 0; tr < 4; ++tr) {
                    int trow = tl0 + tt * 4 + tr;
                    size_t o = (size_t)(b * TC + trow) * (GP / 4) + gblk * 32;
                    float4 v0 = make_float4(acc[tr][0].x + b0.x, acc[tr][0].y + b0.y,
                                            acc[tr][1].x + b0.z, acc[tr][1].y + b0.w);
                    float4 v1 = make_float4(acc[tr][2].x + b1.x, acc[tr][2].y + b1.y,
                                            acc[tr][3].x + b1.z, acc[tr][3].y + b1.w);
                    slot4[o + gt] = v0;
                    slot4[o + 16 + gt] = v1;
                }
            }
            __syncthreads();  // drains all waves' stores before signal
            if (tid == 0) {
                __threadfence();         // release
                atomicAdd(&done[k], 1u);
            }
        }
    }
}

// ---------------- host ----------------
extern "C" void kernel_launch(void* const* d_in, const int* in_sizes, int n_in,
                              void* d_out, int out_size, void* d_ws, size_t ws_size,
                              hipStream_t stream) {
    const float* x    = (const float*)d_in[0];
    const float* W_ih = (const float*)d_in[1];
    const float* W_hh = (const float*)d_in[2];
    const float* b_ih = (const float*)d_in[3];
    const float* b_hh = (const float*)d_in[4];
    float* out = (float*)d_out;

    char* ws = (char*)d_ws;
    float* Wt           = (float*)(ws);            // 200*512*4  = 409600
    float* bias         = (float*)(ws + 409600);   // 512*4      = 2048
    float* Whp          = (float*)(ws + 411648);   // 400*112*4  = 179200 -> 590848
    unsigned int* sync  = (unsigned int*)(ws + 590848);  // 64*4 = 256 -> 591104
    float* xgbuf        = (float*)(ws + 593920);   // ring buffers + 8KB slack

    size_t avail = (ws_size > 593920 + 8192) ? (ws_size - 593920 - 8192) : 0;
    int TC, NB;
    if (avail >= 2ull * B_SZ * 256 * GP * 4)      { TC = 256; NB = 2; }
    else if (avail >= 2ull * B_SZ * 128 * GP * 4) { TC = 128; NB = 2; }
    else                                          { TC = 128; NB = 1; }
    int nch = T_TOTAL / TC;

    prep_kernel<<<400, 256, 0, stream>>>(W_ih, W_hh, b_ih, b_hh, Wt, bias, Whp, sync);
    fused_kernel<<<NBLK, 512, 0, stream>>>(x, Wt, bias, Whp, xgbuf, out, sync,
                                           TC, NB, nch);
}